// Round 17
// baseline (106.563 us; speedup 1.0000x reference)
//
#include <hip/hip_runtime.h>

#define N_NODES 100000
#define N_EDGES 1600000
#define IN_DIM 128
#define H1_DIM 64
#define H2_DIM 32
#define OUT_DIM 16

#define NPB 128                      // src-nodes per bucket
#define KB 782                       // ceil(N_NODES / NPB)
#define NCH 250                      // edge chunks (CH_E int4-aligned)
#define CH_E (N_EDGES / NCH)         // 6400 edges per chunk (exact, /4 = 1600)
#define CH_E4 (CH_E / 4)             // 1600 int4 loads per chunk
#define CAP2 3072                    // per-bucket record cap (mean 2048, +22 sigma)
#define NGB 782                      // ceil(N_NODES / 128) gemmy blocks

typedef __attribute__((ext_vector_type(8))) short short8;
typedef __attribute__((ext_vector_type(4))) float f32x4;

// ---------------- helpers ----------------
__device__ inline unsigned short f2b(float v) {   // RNE f32 -> bf16
    unsigned u = __float_as_uint(v);
    u += 0x7FFF + ((u >> 16) & 1);
    return (unsigned short)(u >> 16);
}
__device__ inline short f2bs(float v) { return (short)f2b(v); }
__device__ inline unsigned f32_to_key(float v) {
    unsigned u = __float_as_uint(v);
    return (v >= 0.f) ? (u | 0x80000000u) : ~u;
}
__device__ __forceinline__ void acc8(float* a, uint4 v) {
    a[0] += __uint_as_float(v.x << 16);
    a[1] += __uint_as_float(v.x & 0xFFFF0000u);
    a[2] += __uint_as_float(v.y << 16);
    a[3] += __uint_as_float(v.y & 0xFFFF0000u);
    a[4] += __uint_as_float(v.z << 16);
    a[5] += __uint_as_float(v.z & 0xFFFF0000u);
    a[6] += __uint_as_float(v.w << 16);
    a[7] += __uint_as_float(v.w & 0xFFFF0000u);
}

// ---------------- bin chunk: 512 threads, int4 edge reads ---------------------
// offT layout TRANSPOSED: offT[bucket * NCH + chunk]  (+ sentinel row KB)
__device__ __forceinline__ void bin_chunk(const int* __restrict__ src,
                                          const int* __restrict__ dst,
                                          unsigned* __restrict__ offT,
                                          unsigned* __restrict__ grec, int c) {
    __shared__ int hist[1024];
    __shared__ int cur[1024];
    __shared__ int bws[8];
    int t = threadIdx.x;
    int e0 = c * CH_E;
    const int4* src4 = (const int4*)(src + e0);
    const int4* dst4 = (const int4*)(dst + e0);
    hist[t] = 0; hist[t + 512] = 0;
    __syncthreads();
    for (int i = t; i < CH_E4; i += 512) {
        int4 s4 = src4[i];
        atomicAdd(&hist[s4.x >> 7], 1);
        atomicAdd(&hist[s4.y >> 7], 1);
        atomicAdd(&hist[s4.z >> 7], 1);
        atomicAdd(&hist[s4.w >> 7], 1);
    }
    __syncthreads();
    int h0 = hist[2 * t], h1 = hist[2 * t + 1];
    int tot = h0 + h1;
    int lane = t & 63, wv = t >> 6;
    int sc = tot;                               // wave-level inclusive scan
    for (int o = 1; o < 64; o <<= 1) {
        int n = __shfl_up(sc, o);
        if (lane >= o) sc += n;
    }
    if (lane == 63) bws[wv] = sc;
    __syncthreads();
    int base = 0;
    for (int k = 0; k < wv; ++k) base += bws[k];
    int gb = base + sc - tot;                   // exclusive prefix of this pair
    int o0 = gb, o1 = gb + h0;
    int b2i = 2 * t;
    cur[b2i] = o0; cur[b2i + 1] = o1;
    if (b2i + 0 < KB) offT[(size_t)(b2i + 0) * NCH + c] = o0;
    if (b2i + 1 < KB) offT[(size_t)(b2i + 1) * NCH + c] = o1;
    if (t == 0) offT[(size_t)KB * NCH + c] = CH_E;   // sentinel row
    __syncthreads();
    for (int i = t; i < CH_E4; i += 512) {
        int4 s4 = src4[i];
        int4 d4 = dst4[i];
        int p;
        p = atomicAdd(&cur[s4.x >> 7], 1);
        grec[(size_t)e0 + p] = ((unsigned)(s4.x & 127) << 17) | (unsigned)d4.x;
        p = atomicAdd(&cur[s4.y >> 7], 1);
        grec[(size_t)e0 + p] = ((unsigned)(s4.y & 127) << 17) | (unsigned)d4.y;
        p = atomicAdd(&cur[s4.z >> 7], 1);
        grec[(size_t)e0 + p] = ((unsigned)(s4.z & 127) << 17) | (unsigned)d4.z;
        p = atomicAdd(&cur[s4.w >> 7], 1);
        grec[(size_t)e0 + p] = ((unsigned)(s4.w & 127) << 17) | (unsigned)d4.w;
    }
}

// ---------------- K1: prep only (1 block): Wcb, cvb, pk=0 ---------------------
__global__ __launch_bounds__(512) void k1_kernel(const float* __restrict__ W1,
                                                 const float* __restrict__ b1,
                                                 const float* __restrict__ W2,
                                                 unsigned short* __restrict__ Wcb,
                                                 float* __restrict__ cvb,
                                                 unsigned* __restrict__ pk) {
    int t = threadIdx.x;
    for (int idx = t; idx < H2_DIM * IN_DIM; idx += 512) {
        int j = idx >> 7, f = idx & 127;
        float acc = 0.f;
        for (int k = 0; k < H1_DIM; ++k)
            acc += W2[j * H1_DIM + k] * W1[k * IN_DIM + f];
        Wcb[idx] = f2b(acc);
    }
    if (t < H2_DIM) {                 // cvb = W2 @ b1 ; pk init (key 0 = min)
        float s = 0.f;
        for (int k = 0; k < H1_DIM; ++k) s += W2[t * H1_DIM + k] * b1[k];
        cvb[t] = s;
        pk[t] = 0u;
    }
}

// ---------------- K2: ALL 250 bin chunks  ||  gemmy (global Wcb, MFMA) --------
__global__ __launch_bounds__(512) void k2_kernel(const int* __restrict__ src,
                                                 const int* __restrict__ dst,
                                                 unsigned* __restrict__ offT,
                                                 unsigned* __restrict__ grec,
                                                 const float* __restrict__ x,
                                                 const unsigned short* __restrict__ Wcb,
                                                 unsigned short* __restrict__ yb) {
    if (blockIdx.x < NCH) {
        bin_chunk(src, dst, offT, grec, blockIdx.x);
        return;
    }
    int gb = blockIdx.x - NCH;
    int t = threadIdx.x;
    int w = t >> 6, l = t & 63;
    int row = l & 15, kg = l >> 4;          // kg in 0..3
    int base = gb * 128 + w * 16;
    int node = base + row;
    int nclamp = (node < N_NODES) ? node : (N_NODES - 1);
    const float* xp = x + (size_t)nclamp * IN_DIM + kg * 8;
    const unsigned short* b0p = Wcb + (size_t)row * IN_DIM + kg * 8;
    const unsigned short* b1p = Wcb + (size_t)(16 + row) * IN_DIM + kg * 8;
    f32x4 acc0 = {0.f, 0.f, 0.f, 0.f}, acc1 = {0.f, 0.f, 0.f, 0.f};
#pragma unroll
    for (int kk = 0; kk < 4; ++kk) {
        float4 xa = *(const float4*)(xp + kk * 32);
        float4 xb = *(const float4*)(xp + kk * 32 + 4);
        short8 a;
        a[0] = f2bs(xa.x); a[1] = f2bs(xa.y); a[2] = f2bs(xa.z); a[3] = f2bs(xa.w);
        a[4] = f2bs(xb.x); a[5] = f2bs(xb.y); a[6] = f2bs(xb.z); a[7] = f2bs(xb.w);
        short8 b0 = *(const short8*)(b0p + kk * 32);
        short8 b1 = *(const short8*)(b1p + kk * 32);
        acc0 = __builtin_amdgcn_mfma_f32_16x16x32_bf16(a, b0, acc0, 0, 0, 0);
        acc1 = __builtin_amdgcn_mfma_f32_16x16x32_bf16(a, b1, acc1, 0, 0, 0);
    }
#pragma unroll
    for (int r = 0; r < 4; ++r) {
        int n2 = base + kg * 4 + r;
        if (n2 < N_NODES) {
            yb[(size_t)n2 * H2_DIM + row]      = f2b(acc0[r]);
            yb[(size_t)n2 * H2_DIM + 16 + row] = f2b(acc1[r]);
        }
    }
}

// ---------------- agg1: sort (fused hist, wave-scans) + gather y -> z1 --------
__global__ __launch_bounds__(512) void agg1_kernel(const unsigned short* __restrict__ in,
                                                   const unsigned* __restrict__ offT,
                                                   const unsigned* __restrict__ grec,
                                                   unsigned* __restrict__ grec2,
                                                   unsigned* __restrict__ noff,
                                                   unsigned short* __restrict__ z1b) {
    __shared__ int pos[NCH + 1], sst[NCH];
    __shared__ int shist[NPB], scur2[NPB];
    __shared__ int sscan[NPB + 1];
    __shared__ int wsum[8], wsum2[8];
    __shared__ unsigned rbuf[CAP2];
    __shared__ unsigned sbuf[CAP2];
    __shared__ int s_cnt;
    int t = threadIdx.x;
    int b = blockIdx.x;
    int gid = t >> 4;              // 32 groups of 16 lanes
    int L = t & 15;
    int chunk = L & 3, subset = L >> 2;
    int lane = t & 63, wv = t >> 6;

    // region table: coalesced 1KB row reads from transposed offT
    int mylen = 0;
    if (t < NCH) {
        unsigned o0 = offT[(size_t)b * NCH + t];
        unsigned o1 = offT[(size_t)(b + 1) * NCH + t];
        sst[t] = (int)o0;
        mylen = (int)(o1 - o0);
    }
    int sc = mylen;                         // unconditional wave-level scan
    for (int o = 1; o < 64; o <<= 1) {
        int n = __shfl_up(sc, o);
        if (lane >= o) sc += n;
    }
    if (lane == 63) wsum[wv] = sc;
    if (t < NPB) shist[t] = 0;
    __syncthreads();
    if (t < NCH) {
        int base = 0;
        for (int k = 0; k < wv; ++k) base += wsum[k];
        pos[t] = base + sc - mylen;         // exclusive
        if (t == NCH - 1) {
            pos[NCH] = base + sc;
            s_cnt = min(base + sc, CAP2);
        }
    }
    __syncthreads();
    int cnt = s_cnt;
    // flat copy + fused histogram: bsearch which chunk-run record i belongs to
    for (int i = t; i < cnt; i += 512) {
        int lo = 0, hi = NCH;               // pos[lo] <= i < pos[hi]
#pragma unroll
        for (int s = 0; s < 8; ++s) {
            int mid = (lo + hi) >> 1;
            if (pos[mid] <= i) lo = mid; else hi = mid;
        }
        unsigned r = grec[(size_t)lo * CH_E + sst[lo] + (i - pos[lo])];
        rbuf[i] = r;
        atomicAdd(&shist[r >> 17], 1);
    }
    __syncthreads();
    int h = (t < NPB) ? shist[t] : 0;
    int sc2 = h;                            // unconditional wave-level scan
    for (int o = 1; o < 64; o <<= 1) {
        int n = __shfl_up(sc2, o);
        if (lane >= o) sc2 += n;
    }
    if (lane == 63) wsum2[wv] = sc2;
    __syncthreads();
    if (t < NPB) {
        int base = (wv == 1) ? wsum2[0] : 0;
        int ex = base + sc2 - h;
        sscan[t] = ex;
        scur2[t] = ex;
        if (t == NPB - 1) sscan[NPB] = base + sc2;
    }
    __syncthreads();
    for (int i = t; i < cnt; i += 512) {
        unsigned r = rbuf[i];
        int p = atomicAdd(&scur2[r >> 17], 1);
        if (p < CAP2) sbuf[p] = r;
    }
    __syncthreads();
    for (int i = t; i < cnt; i += 512) grec2[(size_t)b * CAP2 + i] = sbuf[i];
    if (t < NPB + 1) noff[(size_t)b * (NPB + 1) + t] = (unsigned)sscan[t];

    // gather y -> z1 (32 groups x 4 nodes, 2-quad ILP, shfl_xor(4,8) fold)
    for (int sl = gid; sl < NPB; sl += 32) {
        int r0 = sscan[sl], r1 = sscan[sl + 1];
        float a[8] = {0.f, 0.f, 0.f, 0.f, 0.f, 0.f, 0.f, 0.f};
        float aa[8] = {0.f, 0.f, 0.f, 0.f, 0.f, 0.f, 0.f, 0.f};
        for (int e = r0; e < r1; e += 8) {
            int eA = e + subset, eB = e + 4 + subset;
            if (eA < r1) {
                unsigned rc = sbuf[eA];
                uint4 v = *(const uint4*)(in + (size_t)(rc & 0x1FFFFu) * H2_DIM + chunk * 8);
                acc8(a, v);
            }
            if (eB < r1) {
                unsigned rc = sbuf[eB];
                uint4 v = *(const uint4*)(in + (size_t)(rc & 0x1FFFFu) * H2_DIM + chunk * 8);
                acc8(aa, v);
            }
        }
#pragma unroll
        for (int j = 0; j < 8; ++j) {
            float s = a[j] + aa[j];
            s += __shfl_xor(s, 4);
            s += __shfl_xor(s, 8);
            a[j] = s;
        }
        int node = b * NPB + sl;
        if (node < N_NODES && subset == 0) {
            uint4 o;
            o.x = (unsigned)f2b(a[0]) | ((unsigned)f2b(a[1]) << 16);
            o.y = (unsigned)f2b(a[2]) | ((unsigned)f2b(a[3]) << 16);
            o.z = (unsigned)f2b(a[4]) | ((unsigned)f2b(a[5]) << 16);
            o.w = (unsigned)f2b(a[6]) | ((unsigned)f2b(a[7]) << 16);
            *(uint4*)(z1b + (size_t)node * H2_DIM + chunk * 8) = o;
        }
    }
}

// ---------------- agg2: barrier-free gather z1, 3-quad ILP, fused max-pool ----
__global__ __launch_bounds__(1024) void agg2_kernel(const unsigned short* __restrict__ in,
                                                    const unsigned* __restrict__ grec2,
                                                    const unsigned* __restrict__ noff,
                                                    const float* __restrict__ cvb,
                                                    const float* __restrict__ b2,
                                                    unsigned* __restrict__ pk) {
    __shared__ float smq[64][4][8];
    int t = threadIdx.x;
    int b = blockIdx.x;
    int gid = t >> 4;              // 64 groups of 16 lanes
    int L = t & 15;
    int chunk = L & 3, subset = L >> 2;

    const unsigned* rp = grec2 + (size_t)b * CAP2;
    const unsigned* np = noff + (size_t)b * (NPB + 1);

    float m[8];
#pragma unroll
    for (int j = 0; j < 8; ++j) m[j] = -3.402823466e+38f;

    for (int sl = gid; sl < NPB; sl += 64) {
        int r0 = (int)np[sl], r1 = (int)np[sl + 1];
        float a[8] = {0.f, 0.f, 0.f, 0.f, 0.f, 0.f, 0.f, 0.f};
        float aa[8] = {0.f, 0.f, 0.f, 0.f, 0.f, 0.f, 0.f, 0.f};
        float ac[8] = {0.f, 0.f, 0.f, 0.f, 0.f, 0.f, 0.f, 0.f};
        for (int e = r0; e < r1; e += 12) {
            int eA = e + subset, eB = e + 4 + subset, eC = e + 8 + subset;
            if (eA < r1) {
                unsigned rc = rp[eA];
                uint4 v = *(const uint4*)(in + (size_t)(rc & 0x1FFFFu) * H2_DIM + chunk * 8);
                acc8(a, v);
            }
            if (eB < r1) {
                unsigned rc = rp[eB];
                uint4 v = *(const uint4*)(in + (size_t)(rc & 0x1FFFFu) * H2_DIM + chunk * 8);
                acc8(aa, v);
            }
            if (eC < r1) {
                unsigned rc = rp[eC];
                uint4 v = *(const uint4*)(in + (size_t)(rc & 0x1FFFFu) * H2_DIM + chunk * 8);
                acc8(ac, v);
            }
        }
#pragma unroll
        for (int j = 0; j < 8; ++j) {
            float s = (a[j] + aa[j]) + ac[j];
            s += __shfl_xor(s, 4);
            s += __shfl_xor(s, 8);
            a[j] = s;
        }
        int node = b * NPB + sl;
        if (node < N_NODES) {
            float dg = (float)(r1 - r0);
#pragma unroll
            for (int j = 0; j < 8; ++j)
                m[j] = fmaxf(m[j], a[j] + dg * cvb[chunk * 8 + j] + b2[chunk * 8 + j]);
        }
    }
    if (subset == 0) {
#pragma unroll
        for (int j = 0; j < 8; ++j) smq[gid][chunk][j] = m[j];
    }
    __syncthreads();
    if (t < 32) {                  // feature f == t
        int c = t >> 3, j = t & 7;
        float mm = smq[0][c][j];
#pragma unroll
        for (int k = 1; k < 64; ++k) mm = fmaxf(mm, smq[k][c][j]);
        atomicMax(&pk[t], f32_to_key(mm));
    }
}

// ---------------- out = pooled @ Wf^T + bf ----------------
__global__ void final_kernel(const unsigned* __restrict__ pk,
                             const float* __restrict__ Wf,
                             const float* __restrict__ bfv,
                             float* __restrict__ out) {
    __shared__ float pooled[H2_DIM];
    int t = threadIdx.x;
    if (t < H2_DIM) {
        unsigned k = pk[t];
        unsigned u = (k & 0x80000000u) ? (k & 0x7FFFFFFFu) : ~k;
        pooled[t] = __uint_as_float(u);
    }
    __syncthreads();
    if (t < OUT_DIM) {
        float acc = bfv[t];
        for (int j = 0; j < H2_DIM; ++j)
            acc += Wf[t * H2_DIM + j] * pooled[j];
        out[t] = acc;
    }
}

extern "C" void kernel_launch(void* const* d_in, const int* in_sizes, int n_in,
                              void* d_out, int out_size, void* d_ws, size_t ws_size,
                              hipStream_t stream) {
    const float* x  = (const float*)d_in[0];
    const int*   ei = (const int*)d_in[1];           // [2, E]: row0 = src, row1 = dst
    const float* W1 = (const float*)d_in[2];
    const float* b1 = (const float*)d_in[3];
    const float* W2 = (const float*)d_in[4];
    const float* b2 = (const float*)d_in[5];
    const float* Wf = (const float*)d_in[6];
    const float* bf = (const float*)d_in[7];
    float* out = (float*)d_out;

    const int* src = ei;
    const int* dst = ei + N_EDGES;

    // workspace carve-up (~30 MB)
    unsigned short* yb  = (unsigned short*)d_ws;                 // N*32 bf16
    unsigned short* z1b = yb + (size_t)N_NODES * H2_DIM;         // N*32 bf16
    unsigned short* Wcb = z1b + (size_t)N_NODES * H2_DIM;        // 32*128 bf16
    float* cvb      = (float*)(Wcb + H2_DIM * IN_DIM);           // 32
    unsigned* pk    = (unsigned*)(cvb + H2_DIM);                 // 32
    unsigned* offT  = pk + H2_DIM;                               // (KB+1)*NCH
    unsigned* grec  = offT + (size_t)(KB + 1) * NCH;             // N_EDGES
    unsigned* grec2 = grec + N_EDGES;                            // KB*CAP2
    unsigned* noff  = grec2 + (size_t)KB * CAP2;                 // KB*(NPB+1)

    k1_kernel<<<1, 512, 0, stream>>>(W1, b1, W2, Wcb, cvb, pk);
    k2_kernel<<<NCH + NGB, 512, 0, stream>>>(src, dst, offT, grec, x, Wcb, yb);

    agg1_kernel<<<KB, 512, 0, stream>>>(yb, offT, grec, grec2, noff, z1b);
    agg2_kernel<<<KB, 1024, 0, stream>>>(z1b, grec2, noff, cvb, b2, pk);

    final_kernel<<<1, 64, 0, stream>>>(pk, Wf, bf, out);
}

// Round 18
// 102.428 us; speedup vs baseline: 1.0404x; 1.0404x over previous
//
#include <hip/hip_runtime.h>

#define N_NODES 100000
#define N_EDGES 1600000
#define IN_DIM 128
#define H1_DIM 64
#define H2_DIM 32
#define OUT_DIM 16

#define NPB 128                      // src-nodes per bucket
#define KB 782                       // ceil(N_NODES / NPB)
#define NCH 250                      // edge chunks (CH_E int4-aligned)
#define CH_E (N_EDGES / NCH)         // 6400 edges per chunk (exact, /4 = 1600)
#define CH_E4 (CH_E / 4)             // 1600 int4 loads per chunk
#define CAP2 3072                    // per-bucket record cap (mean 2048, +22 sigma)
#define NBIN1 64                     // bin chunks done in K1 (with prep)
#define NBIN2 (NCH - NBIN1)          // bin chunks done in K2 (with gemmy)
#define NGB 782                      // ceil(N_NODES / 128) gemmy blocks

typedef __attribute__((ext_vector_type(8))) short short8;
typedef __attribute__((ext_vector_type(4))) float f32x4;

// ---------------- helpers ----------------
__device__ inline unsigned short f2b(float v) {   // RNE f32 -> bf16
    unsigned u = __float_as_uint(v);
    u += 0x7FFF + ((u >> 16) & 1);
    return (unsigned short)(u >> 16);
}
__device__ inline short f2bs(float v) { return (short)f2b(v); }
__device__ inline unsigned f32_to_key(float v) {
    unsigned u = __float_as_uint(v);
    return (v >= 0.f) ? (u | 0x80000000u) : ~u;
}
__device__ __forceinline__ void acc8(float* a, uint4 v) {
    a[0] += __uint_as_float(v.x << 16);
    a[1] += __uint_as_float(v.x & 0xFFFF0000u);
    a[2] += __uint_as_float(v.y << 16);
    a[3] += __uint_as_float(v.y & 0xFFFF0000u);
    a[4] += __uint_as_float(v.z << 16);
    a[5] += __uint_as_float(v.z & 0xFFFF0000u);
    a[6] += __uint_as_float(v.w << 16);
    a[7] += __uint_as_float(v.w & 0xFFFF0000u);
}

// ---------------- bin chunk: 512 threads, int4 edge reads ---------------------
// offT layout TRANSPOSED: offT[bucket * NCH + chunk]  (+ sentinel row KB)
__device__ __forceinline__ void bin_chunk(const int* __restrict__ src,
                                          const int* __restrict__ dst,
                                          unsigned* __restrict__ offT,
                                          unsigned* __restrict__ grec, int c) {
    __shared__ int hist[1024];
    __shared__ int cur[1024];
    __shared__ int bws[8];
    int t = threadIdx.x;
    int e0 = c * CH_E;
    const int4* src4 = (const int4*)(src + e0);
    const int4* dst4 = (const int4*)(dst + e0);
    hist[t] = 0; hist[t + 512] = 0;
    __syncthreads();
    for (int i = t; i < CH_E4; i += 512) {
        int4 s4 = src4[i];
        atomicAdd(&hist[s4.x >> 7], 1);
        atomicAdd(&hist[s4.y >> 7], 1);
        atomicAdd(&hist[s4.z >> 7], 1);
        atomicAdd(&hist[s4.w >> 7], 1);
    }
    __syncthreads();
    int h0 = hist[2 * t], h1 = hist[2 * t + 1];
    int tot = h0 + h1;
    int lane = t & 63, wv = t >> 6;
    int sc = tot;                               // wave-level inclusive scan
    for (int o = 1; o < 64; o <<= 1) {
        int n = __shfl_up(sc, o);
        if (lane >= o) sc += n;
    }
    if (lane == 63) bws[wv] = sc;
    __syncthreads();
    int base = 0;
    for (int k = 0; k < wv; ++k) base += bws[k];
    int gb = base + sc - tot;                   // exclusive prefix of this pair
    int o0 = gb, o1 = gb + h0;
    int b2i = 2 * t;
    cur[b2i] = o0; cur[b2i + 1] = o1;
    if (b2i + 0 < KB) offT[(size_t)(b2i + 0) * NCH + c] = o0;
    if (b2i + 1 < KB) offT[(size_t)(b2i + 1) * NCH + c] = o1;
    if (t == 0) offT[(size_t)KB * NCH + c] = CH_E;   // sentinel row
    __syncthreads();
    for (int i = t; i < CH_E4; i += 512) {
        int4 s4 = src4[i];
        int4 d4 = dst4[i];
        int p;
        p = atomicAdd(&cur[s4.x >> 7], 1);
        grec[(size_t)e0 + p] = ((unsigned)(s4.x & 127) << 17) | (unsigned)d4.x;
        p = atomicAdd(&cur[s4.y >> 7], 1);
        grec[(size_t)e0 + p] = ((unsigned)(s4.y & 127) << 17) | (unsigned)d4.y;
        p = atomicAdd(&cur[s4.z >> 7], 1);
        grec[(size_t)e0 + p] = ((unsigned)(s4.z & 127) << 17) | (unsigned)d4.z;
        p = atomicAdd(&cur[s4.w >> 7], 1);
        grec[(size_t)e0 + p] = ((unsigned)(s4.w & 127) << 17) | (unsigned)d4.w;
    }
}

// ---------------- K1: bin chunks 0..NBIN1-1  ||  prep (Wcb, cvb, pk=0) --------
__global__ __launch_bounds__(512) void k1_kernel(const int* __restrict__ src,
                                                 const int* __restrict__ dst,
                                                 unsigned* __restrict__ offT,
                                                 unsigned* __restrict__ grec,
                                                 const float* __restrict__ W1,
                                                 const float* __restrict__ b1,
                                                 const float* __restrict__ W2,
                                                 unsigned short* __restrict__ Wcb,
                                                 float* __restrict__ cvb,
                                                 unsigned* __restrict__ pk) {
    if (blockIdx.x < NBIN1) {
        bin_chunk(src, dst, offT, grec, blockIdx.x);
        return;
    }
    int t = threadIdx.x;
    for (int idx = t; idx < H2_DIM * IN_DIM; idx += 512) {
        int j = idx >> 7, f = idx & 127;
        float acc = 0.f;
        for (int k = 0; k < H1_DIM; ++k)
            acc += W2[j * H1_DIM + k] * W1[k * IN_DIM + f];
        Wcb[idx] = f2b(acc);
    }
    if (t < H2_DIM) {                 // cvb = W2 @ b1 ; pk init (key 0 = min)
        float s = 0.f;
        for (int k = 0; k < H1_DIM; ++k) s += W2[t * H1_DIM + k] * b1[k];
        cvb[t] = s;
        pk[t] = 0u;
    }
}

// ---------------- K2: bin chunks NBIN1..NCH-1  ||  gemmy (global Wcb, MFMA) ---
__global__ __launch_bounds__(512) void k2_kernel(const int* __restrict__ src,
                                                 const int* __restrict__ dst,
                                                 unsigned* __restrict__ offT,
                                                 unsigned* __restrict__ grec,
                                                 const float* __restrict__ x,
                                                 const unsigned short* __restrict__ Wcb,
                                                 unsigned short* __restrict__ yb) {
    if (blockIdx.x < NBIN2) {
        bin_chunk(src, dst, offT, grec, NBIN1 + blockIdx.x);
        return;
    }
    int gb = blockIdx.x - NBIN2;
    int t = threadIdx.x;
    int w = t >> 6, l = t & 63;
    int row = l & 15, kg = l >> 4;          // kg in 0..3
    int base = gb * 128 + w * 16;
    int node = base + row;
    int nclamp = (node < N_NODES) ? node : (N_NODES - 1);
    const float* xp = x + (size_t)nclamp * IN_DIM + kg * 8;
    const unsigned short* b0p = Wcb + (size_t)row * IN_DIM + kg * 8;
    const unsigned short* b1p = Wcb + (size_t)(16 + row) * IN_DIM + kg * 8;
    f32x4 acc0 = {0.f, 0.f, 0.f, 0.f}, acc1 = {0.f, 0.f, 0.f, 0.f};
#pragma unroll
    for (int kk = 0; kk < 4; ++kk) {
        float4 xa = *(const float4*)(xp + kk * 32);
        float4 xb = *(const float4*)(xp + kk * 32 + 4);
        short8 a;
        a[0] = f2bs(xa.x); a[1] = f2bs(xa.y); a[2] = f2bs(xa.z); a[3] = f2bs(xa.w);
        a[4] = f2bs(xb.x); a[5] = f2bs(xb.y); a[6] = f2bs(xb.z); a[7] = f2bs(xb.w);
        short8 b0 = *(const short8*)(b0p + kk * 32);
        short8 b1 = *(const short8*)(b1p + kk * 32);
        acc0 = __builtin_amdgcn_mfma_f32_16x16x32_bf16(a, b0, acc0, 0, 0, 0);
        acc1 = __builtin_amdgcn_mfma_f32_16x16x32_bf16(a, b1, acc1, 0, 0, 0);
    }
#pragma unroll
    for (int r = 0; r < 4; ++r) {
        int n2 = base + kg * 4 + r;
        if (n2 < N_NODES) {
            yb[(size_t)n2 * H2_DIM + row]      = f2b(acc0[r]);
            yb[(size_t)n2 * H2_DIM + 16 + row] = f2b(acc1[r]);
        }
    }
}

// ---------------- agg1: sort (fused hist, wave-scans) + gather y -> z1 --------
__global__ __launch_bounds__(512) void agg1_kernel(const unsigned short* __restrict__ in,
                                                   const unsigned* __restrict__ offT,
                                                   const unsigned* __restrict__ grec,
                                                   unsigned* __restrict__ grec2,
                                                   unsigned* __restrict__ noff,
                                                   unsigned short* __restrict__ z1b) {
    __shared__ int pos[NCH + 1], sst[NCH];
    __shared__ int shist[NPB], scur2[NPB];
    __shared__ int sscan[NPB + 1];
    __shared__ int wsum[8], wsum2[8];
    __shared__ unsigned rbuf[CAP2];
    __shared__ unsigned sbuf[CAP2];
    __shared__ int s_cnt;
    int t = threadIdx.x;
    int b = blockIdx.x;
    int gid = t >> 4;              // 32 groups of 16 lanes
    int L = t & 15;
    int chunk = L & 3, subset = L >> 2;
    int lane = t & 63, wv = t >> 6;

    // region table: coalesced 1KB row reads from transposed offT
    int mylen = 0;
    if (t < NCH) {
        unsigned o0 = offT[(size_t)b * NCH + t];
        unsigned o1 = offT[(size_t)(b + 1) * NCH + t];
        sst[t] = (int)o0;
        mylen = (int)(o1 - o0);
    }
    int sc = mylen;                         // unconditional wave-level scan
    for (int o = 1; o < 64; o <<= 1) {
        int n = __shfl_up(sc, o);
        if (lane >= o) sc += n;
    }
    if (lane == 63) wsum[wv] = sc;
    if (t < NPB) shist[t] = 0;
    __syncthreads();
    if (t < NCH) {
        int base = 0;
        for (int k = 0; k < wv; ++k) base += wsum[k];
        pos[t] = base + sc - mylen;         // exclusive
        if (t == NCH - 1) {
            pos[NCH] = base + sc;
            s_cnt = min(base + sc, CAP2);
        }
    }
    __syncthreads();
    int cnt = s_cnt;
    // flat copy + fused histogram: bsearch which chunk-run record i belongs to
    for (int i = t; i < cnt; i += 512) {
        int lo = 0, hi = NCH;               // pos[lo] <= i < pos[hi]
#pragma unroll
        for (int s = 0; s < 8; ++s) {
            int mid = (lo + hi) >> 1;
            if (pos[mid] <= i) lo = mid; else hi = mid;
        }
        unsigned r = grec[(size_t)lo * CH_E + sst[lo] + (i - pos[lo])];
        rbuf[i] = r;
        atomicAdd(&shist[r >> 17], 1);
    }
    __syncthreads();
    int h = (t < NPB) ? shist[t] : 0;
    int sc2 = h;                            // unconditional wave-level scan
    for (int o = 1; o < 64; o <<= 1) {
        int n = __shfl_up(sc2, o);
        if (lane >= o) sc2 += n;
    }
    if (lane == 63) wsum2[wv] = sc2;
    __syncthreads();
    if (t < NPB) {
        int base = (wv == 1) ? wsum2[0] : 0;
        int ex = base + sc2 - h;
        sscan[t] = ex;
        scur2[t] = ex;
        if (t == NPB - 1) sscan[NPB] = base + sc2;
    }
    __syncthreads();
    for (int i = t; i < cnt; i += 512) {
        unsigned r = rbuf[i];
        int p = atomicAdd(&scur2[r >> 17], 1);
        if (p < CAP2) sbuf[p] = r;
    }
    __syncthreads();
    for (int i = t; i < cnt; i += 512) grec2[(size_t)b * CAP2 + i] = sbuf[i];
    if (t < NPB + 1) noff[(size_t)b * (NPB + 1) + t] = (unsigned)sscan[t];

    // gather y -> z1 (32 groups x 4 nodes, 2-quad ILP, shfl_xor(4,8) fold)
    for (int sl = gid; sl < NPB; sl += 32) {
        int r0 = sscan[sl], r1 = sscan[sl + 1];
        float a[8] = {0.f, 0.f, 0.f, 0.f, 0.f, 0.f, 0.f, 0.f};
        float aa[8] = {0.f, 0.f, 0.f, 0.f, 0.f, 0.f, 0.f, 0.f};
        for (int e = r0; e < r1; e += 8) {
            int eA = e + subset, eB = e + 4 + subset;
            if (eA < r1) {
                unsigned rc = sbuf[eA];
                uint4 v = *(const uint4*)(in + (size_t)(rc & 0x1FFFFu) * H2_DIM + chunk * 8);
                acc8(a, v);
            }
            if (eB < r1) {
                unsigned rc = sbuf[eB];
                uint4 v = *(const uint4*)(in + (size_t)(rc & 0x1FFFFu) * H2_DIM + chunk * 8);
                acc8(aa, v);
            }
        }
#pragma unroll
        for (int j = 0; j < 8; ++j) {
            float s = a[j] + aa[j];
            s += __shfl_xor(s, 4);
            s += __shfl_xor(s, 8);
            a[j] = s;
        }
        int node = b * NPB + sl;
        if (node < N_NODES && subset == 0) {
            uint4 o;
            o.x = (unsigned)f2b(a[0]) | ((unsigned)f2b(a[1]) << 16);
            o.y = (unsigned)f2b(a[2]) | ((unsigned)f2b(a[3]) << 16);
            o.z = (unsigned)f2b(a[4]) | ((unsigned)f2b(a[5]) << 16);
            o.w = (unsigned)f2b(a[6]) | ((unsigned)f2b(a[7]) << 16);
            *(uint4*)(z1b + (size_t)node * H2_DIM + chunk * 8) = o;
        }
    }
}

// ---------------- agg2: barrier-free gather z1, 3-quad ILP, fused max-pool ----
__global__ __launch_bounds__(1024) void agg2_kernel(const unsigned short* __restrict__ in,
                                                    const unsigned* __restrict__ grec2,
                                                    const unsigned* __restrict__ noff,
                                                    const float* __restrict__ cvb,
                                                    const float* __restrict__ b2,
                                                    unsigned* __restrict__ pk) {
    __shared__ float smq[64][4][8];
    int t = threadIdx.x;
    int b = blockIdx.x;
    int gid = t >> 4;              // 64 groups of 16 lanes
    int L = t & 15;
    int chunk = L & 3, subset = L >> 2;

    const unsigned* rp = grec2 + (size_t)b * CAP2;
    const unsigned* np = noff + (size_t)b * (NPB + 1);

    float m[8];
#pragma unroll
    for (int j = 0; j < 8; ++j) m[j] = -3.402823466e+38f;

    for (int sl = gid; sl < NPB; sl += 64) {
        int r0 = (int)np[sl], r1 = (int)np[sl + 1];
        float a[8] = {0.f, 0.f, 0.f, 0.f, 0.f, 0.f, 0.f, 0.f};
        float aa[8] = {0.f, 0.f, 0.f, 0.f, 0.f, 0.f, 0.f, 0.f};
        float ac[8] = {0.f, 0.f, 0.f, 0.f, 0.f, 0.f, 0.f, 0.f};
        for (int e = r0; e < r1; e += 12) {
            int eA = e + subset, eB = e + 4 + subset, eC = e + 8 + subset;
            if (eA < r1) {
                unsigned rc = rp[eA];
                uint4 v = *(const uint4*)(in + (size_t)(rc & 0x1FFFFu) * H2_DIM + chunk * 8);
                acc8(a, v);
            }
            if (eB < r1) {
                unsigned rc = rp[eB];
                uint4 v = *(const uint4*)(in + (size_t)(rc & 0x1FFFFu) * H2_DIM + chunk * 8);
                acc8(aa, v);
            }
            if (eC < r1) {
                unsigned rc = rp[eC];
                uint4 v = *(const uint4*)(in + (size_t)(rc & 0x1FFFFu) * H2_DIM + chunk * 8);
                acc8(ac, v);
            }
        }
#pragma unroll
        for (int j = 0; j < 8; ++j) {
            float s = (a[j] + aa[j]) + ac[j];
            s += __shfl_xor(s, 4);
            s += __shfl_xor(s, 8);
            a[j] = s;
        }
        int node = b * NPB + sl;
        if (node < N_NODES) {
            float dg = (float)(r1 - r0);
#pragma unroll
            for (int j = 0; j < 8; ++j)
                m[j] = fmaxf(m[j], a[j] + dg * cvb[chunk * 8 + j] + b2[chunk * 8 + j]);
        }
    }
    if (subset == 0) {
#pragma unroll
        for (int j = 0; j < 8; ++j) smq[gid][chunk][j] = m[j];
    }
    __syncthreads();
    if (t < 32) {                  // feature f == t
        int c = t >> 3, j = t & 7;
        float mm = smq[0][c][j];
#pragma unroll
        for (int k = 1; k < 64; ++k) mm = fmaxf(mm, smq[k][c][j]);
        atomicMax(&pk[t], f32_to_key(mm));
    }
}

// ---------------- out = pooled @ Wf^T + bf ----------------
__global__ void final_kernel(const unsigned* __restrict__ pk,
                             const float* __restrict__ Wf,
                             const float* __restrict__ bfv,
                             float* __restrict__ out) {
    __shared__ float pooled[H2_DIM];
    int t = threadIdx.x;
    if (t < H2_DIM) {
        unsigned k = pk[t];
        unsigned u = (k & 0x80000000u) ? (k & 0x7FFFFFFFu) : ~k;
        pooled[t] = __uint_as_float(u);
    }
    __syncthreads();
    if (t < OUT_DIM) {
        float acc = bfv[t];
        for (int j = 0; j < H2_DIM; ++j)
            acc += Wf[t * H2_DIM + j] * pooled[j];
        out[t] = acc;
    }
}

extern "C" void kernel_launch(void* const* d_in, const int* in_sizes, int n_in,
                              void* d_out, int out_size, void* d_ws, size_t ws_size,
                              hipStream_t stream) {
    const float* x  = (const float*)d_in[0];
    const int*   ei = (const int*)d_in[1];           // [2, E]: row0 = src, row1 = dst
    const float* W1 = (const float*)d_in[2];
    const float* b1 = (const float*)d_in[3];
    const float* W2 = (const float*)d_in[4];
    const float* b2 = (const float*)d_in[5];
    const float* Wf = (const float*)d_in[6];
    const float* bf = (const float*)d_in[7];
    float* out = (float*)d_out;

    const int* src = ei;
    const int* dst = ei + N_EDGES;

    // workspace carve-up (~30 MB)
    unsigned short* yb  = (unsigned short*)d_ws;                 // N*32 bf16
    unsigned short* z1b = yb + (size_t)N_NODES * H2_DIM;         // N*32 bf16
    unsigned short* Wcb = z1b + (size_t)N_NODES * H2_DIM;        // 32*128 bf16
    float* cvb      = (float*)(Wcb + H2_DIM * IN_DIM);           // 32
    unsigned* pk    = (unsigned*)(cvb + H2_DIM);                 // 32
    unsigned* offT  = pk + H2_DIM;                               // (KB+1)*NCH
    unsigned* grec  = offT + (size_t)(KB + 1) * NCH;             // N_EDGES
    unsigned* grec2 = grec + N_EDGES;                            // KB*CAP2
    unsigned* noff  = grec2 + (size_t)KB * CAP2;                 // KB*(NPB+1)

    k1_kernel<<<NBIN1 + 1, 512, 0, stream>>>(src, dst, offT, grec, W1, b1, W2,
                                             Wcb, cvb, pk);
    k2_kernel<<<NBIN2 + NGB, 512, 0, stream>>>(src, dst, offT, grec, x, Wcb, yb);

    agg1_kernel<<<KB, 512, 0, stream>>>(yb, offT, grec, grec2, noff, z1b);
    agg2_kernel<<<KB, 1024, 0, stream>>>(z1b, grec2, noff, cvb, b2, pk);

    final_kernel<<<1, 64, 0, stream>>>(pk, Wf, bf, out);
}